// Round 11
// baseline (209.661 us; speedup 1.0000x reference)
//
#include <hip/hip_runtime.h>
#include <cstdint>
#include <cstddef>

// ---------------------------------------------------------------------------
// ReLA block: y = LN2( (causal_relu( (LN1(x)Wq*s) (LN1(x)Wk)^T ) (LN1(x)Wv)) Wout )
// x: [2,2048,1024] fp32. HEADS=16, DIM_HEAD=64, DIM=1024. Output fp32.
// bf16 MFMA (16x16x32) everywhere, fp32 accumulate.
// R10: (a) vtrans eliminated — gemm<1> writes the V quadrant directly in
//      V^T layout (C-layout reg r varies pos -> packed bf16x4 stores);
//      (b) attn drops Vts staging (V fragments direct from L2-resident
//      global), LDS 73->41KB -> 3 blocks/CU at (256,3); sequential units
//      keep VGPRs under the 3-waves/EU cap (~170).
// ---------------------------------------------------------------------------

typedef __bf16 bf16_t;
typedef __bf16 bf16x8 __attribute__((ext_vector_type(8)));
typedef __bf16 bf16x4 __attribute__((ext_vector_type(4)));
typedef float  f32x4  __attribute__((ext_vector_type(4)));

#define DEV_INLINE __device__ __forceinline__

// async global->LDS, 16B per lane. LDS dest is wave-uniform base + lane*16.
DEV_INLINE void async_copy16(void* lds, const void* g) {
  __builtin_amdgcn_global_load_lds(
      (__attribute__((address_space(1))) void*)(g),
      (__attribute__((address_space(3))) void*)(lds), 16, 0, 0);
}

// ---------------------------------------------------------------------------
// prep: fused LN1 (blocks 0..4095) + wtrans(w_qkv) (4096..4863) +
//       wtrans(w_out) (4864..5119)
// ---------------------------------------------------------------------------
__global__ __launch_bounds__(256) void prep_kernel(
    const float* __restrict__ x, const float* __restrict__ g1,
    const float* __restrict__ b1, bf16_t* __restrict__ xn,
    const float* __restrict__ w_qkv, bf16_t* __restrict__ wqkvT,
    const float* __restrict__ w_out, bf16_t* __restrict__ woutT) {
  const int bid = blockIdx.x;
  const int t = threadIdx.x;
  if (bid < 4096) {
    // ---- LN1 row ----
    const int w = t >> 6, l = t & 63;
    const float* xr = x + (size_t)bid * 1024;
    float4 v = *(const float4*)(xr + t * 4);
    float s  = v.x + v.y + v.z + v.w;
    float s2 = v.x * v.x + v.y * v.y + v.z * v.z + v.w * v.w;
    #pragma unroll
    for (int off = 32; off >= 1; off >>= 1) {
      s  += __shfl_down(s, off);
      s2 += __shfl_down(s2, off);
    }
    __shared__ float red[8];
    if (l == 0) { red[w] = s; red[4 + w] = s2; }
    __syncthreads();
    s  = red[0] + red[1] + red[2] + red[3];
    s2 = red[4] + red[5] + red[6] + red[7];
    float mu  = s * (1.0f / 1024.0f);
    float var = s2 * (1.0f / 1024.0f) - mu * mu;
    float rs  = rsqrtf(var + 1e-5f);
    float4 gv = *(const float4*)(g1 + t * 4);
    float4 bv = *(const float4*)(b1 + t * 4);
    bf16x4 o;
    o[0] = (bf16_t)((v.x - mu) * rs * gv.x + bv.x);
    o[1] = (bf16_t)((v.y - mu) * rs * gv.y + bv.y);
    o[2] = (bf16_t)((v.z - mu) * rs * gv.z + bv.z);
    o[3] = (bf16_t)((v.w - mu) * rs * gv.w + bv.w);
    *(bf16x4*)(xn + (size_t)bid * 1024 + t * 4) = o;
  } else {
    // ---- weight transpose+convert: 64x64 tile ----
    const float* wsrc; bf16_t* wdst; int N, tile;
    if (bid < 4864) { wsrc = w_qkv; wdst = wqkvT; N = 3072; tile = bid - 4096; }
    else            { wsrc = w_out; wdst = woutT; N = 1024; tile = bid - 4864; }
    const int ntiles = N >> 6;
    const int n0 = (tile % ntiles) * 64, k0 = (tile / ntiles) * 64;
    __shared__ __align__(16) float tl[64][68];
    #pragma unroll
    for (int c = 0; c < 4; ++c) {
      int idx = c * 256 + t;
      int r = idx >> 4, c4 = (idx & 15) * 4;
      *(float4*)&tl[r][c4] = *(const float4*)(wsrc + (size_t)(k0 + r) * N + n0 + c4);
    }
    __syncthreads();
    #pragma unroll
    for (int c = 0; c < 2; ++c) {
      int idx = c * 256 + t;
      int nl = idx >> 3, kc = (idx & 7) * 8;
      bf16x8 o;
      #pragma unroll
      for (int ii = 0; ii < 8; ++ii) o[ii] = (bf16_t)tl[kc + ii][nl];
      *(bf16x8*)(wdst + (size_t)(n0 + nl) * 1024 + k0 + kc) = o;
    }
  }
}

// ---------------------------------------------------------------------------
// LN2 (fused split-K add, bf16 partials): z = z0 + z1 -> layernorm -> fp32
// ---------------------------------------------------------------------------
__global__ __launch_bounds__(256) void ln2_kernel(
    const bf16_t* __restrict__ z0, const bf16_t* __restrict__ z1,
    const float* __restrict__ g, const float* __restrict__ bta,
    float* __restrict__ out) {
  const int row = blockIdx.x;
  const int t = threadIdx.x, w = t >> 6, l = t & 63;
  bf16x4 a0 = *(const bf16x4*)(z0 + (size_t)row * 1024 + t * 4);
  bf16x4 a1 = *(const bf16x4*)(z1 + (size_t)row * 1024 + t * 4);
  float4 v;
  v.x = (float)a0[0] + (float)a1[0];
  v.y = (float)a0[1] + (float)a1[1];
  v.z = (float)a0[2] + (float)a1[2];
  v.w = (float)a0[3] + (float)a1[3];
  float s  = v.x + v.y + v.z + v.w;
  float s2 = v.x * v.x + v.y * v.y + v.z * v.z + v.w * v.w;
  #pragma unroll
  for (int off = 32; off >= 1; off >>= 1) {
    s  += __shfl_down(s, off);
    s2 += __shfl_down(s2, off);
  }
  __shared__ float red[8];
  if (l == 0) { red[w] = s; red[4 + w] = s2; }
  __syncthreads();
  s  = red[0] + red[1] + red[2] + red[3];
  s2 = red[4] + red[5] + red[6] + red[7];
  float mu  = s * (1.0f / 1024.0f);
  float var = s2 * (1.0f / 1024.0f) - mu * mu;
  float rs  = rsqrtf(var + 1e-5f);
  float4 gv = *(const float4*)(g + t * 4);
  float4 bv = *(const float4*)(bta + t * 4);
  float4 o;
  o.x = (v.x - mu) * rs * gv.x + bv.x;
  o.y = (v.y - mu) * rs * gv.y + bv.y;
  o.z = (v.z - mu) * rs * gv.z + bv.z;
  o.w = (v.w - mu) * rs * gv.w + bv.w;
  *(float4*)(out + (size_t)row * 1024 + t * 4) = o;
}

// ---------------------------------------------------------------------------
// GEMM: C[M,N] = A[M,1024] @ Bt[N,1024]^T, bf16 in, fp32 acc.
// BK=64, XOR-swizzled staging. KSPLIT=2: kz=0 -> C0, kz=1 -> C1 (bf16
// partials). EPI=1: qkv epilogue -> q(*0.125)/k as [b,h,2048,64] bf16,
// v directly TRANSPOSED as vT [b,h,64,2048] (packed bf16x4, r = pos).
// ---------------------------------------------------------------------------
template <int EPI, int KSPLIT>
__global__ __launch_bounds__(256, 3) void gemm128_kernel(
    const bf16_t* __restrict__ A, const bf16_t* __restrict__ Bt,
    void* __restrict__ C0, void* __restrict__ C1, void* __restrict__ C2) {
  __shared__ __align__(16) bf16_t As[128 * 64];  // 16 KB
  __shared__ __align__(16) bf16_t Bs[128 * 64];  // 16 KB
  const int t = threadIdx.x;
  const int w = t >> 6, l = t & 63, l15 = l & 15, quad = l >> 4;
  const int wy = w >> 1, wx = w & 1;
  const int m0 = blockIdx.y * 128, n0 = blockIdx.x * 128;
  const int kz = (KSPLIT > 1) ? blockIdx.z : 0;
  const int kt0 = kz * (16 / KSPLIT), kt1 = kt0 + (16 / KSPLIT);

  const int r_l = l >> 3;              // row within 8-row chunk
  const int u_src = (l & 7) ^ r_l;     // swizzled source 8-elem unit
  const int rswz = l15 & 7;            // read-side swizzle key

  f32x4 acc[4][4];
  #pragma unroll
  for (int i = 0; i < 4; ++i)
    #pragma unroll
    for (int j = 0; j < 4; ++j) acc[i][j] = (f32x4)0.0f;

  for (int kt = kt0; kt < kt1; ++kt) {
    __syncthreads();
    #pragma unroll
    for (int c = 0; c < 4; ++c) {
      int idx = w * 4 + c;             // 16 chunks of 512 elems
      int row = idx * 8 + r_l;         // 0..127
      async_copy16(&As[idx * 512], A + (size_t)(m0 + row) * 1024 + kt * 64 + u_src * 8);
      async_copy16(&Bs[idx * 512], Bt + (size_t)(n0 + row) * 1024 + kt * 64 + u_src * 8);
    }
    __syncthreads();
    #pragma unroll
    for (int kk = 0; kk < 2; ++kk) {
      bf16x8 af[4], bfr[4];
      #pragma unroll
      for (int i = 0; i < 4; ++i)
        af[i] = *(const bf16x8*)&As[(wy * 64 + i * 16 + l15) * 64 + (((kk * 4 + quad) ^ rswz) * 8)];
      #pragma unroll
      for (int j = 0; j < 4; ++j)
        bfr[j] = *(const bf16x8*)&Bs[(wx * 64 + j * 16 + l15) * 64 + (((kk * 4 + quad) ^ rswz) * 8)];
      #pragma unroll
      for (int i = 0; i < 4; ++i)
        #pragma unroll
        for (int j = 0; j < 4; ++j)
          acc[i][j] = __builtin_amdgcn_mfma_f32_16x16x32_bf16(af[i], bfr[j], acc[i][j], 0, 0, 0);
    }
  }

  if (EPI == 0) {
    bf16_t* C = (bf16_t*)(kz == 0 ? C0 : C1);   // bf16 partial destinations
    #pragma unroll
    for (int i = 0; i < 4; ++i)
      #pragma unroll
      for (int j = 0; j < 4; ++j)
        #pragma unroll
        for (int r = 0; r < 4; ++r) {
          int m = m0 + wy * 64 + i * 16 + quad * 4 + r;
          int n = n0 + wx * 64 + j * 16 + l15;
          C[(size_t)m * 1024 + n] = (bf16_t)acc[i][j][r];
        }
  } else {
    int nb = n0 + wx * 64;
    int which = nb >> 10;                 // 0=q, 1=k, 2=v
    int head = (nb & 1023) >> 6;
    if (which < 2) {
      bf16_t* dst = which == 0 ? (bf16_t*)C0 : (bf16_t*)C1;
      float sc = which == 0 ? 0.125f : 1.0f;
      #pragma unroll
      for (int i = 0; i < 4; ++i)
        #pragma unroll
        for (int j = 0; j < 4; ++j)
          #pragma unroll
          for (int r = 0; r < 4; ++r) {
            int m = m0 + wy * 64 + i * 16 + quad * 4 + r;
            int bq = m >> 11, pos = m & 2047;
            int d = j * 16 + l15;
            dst[(((size_t)(bq * 16 + head)) * 2048 + pos) * 64 + d] =
                (bf16_t)(acc[i][j][r] * sc);
          }
    } else {
      // v written directly transposed: vT[b,h,64,2048]; reg r = pos-contig
      bf16_t* vT = (bf16_t*)C2;
      #pragma unroll
      for (int i = 0; i < 4; ++i)
        #pragma unroll
        for (int j = 0; j < 4; ++j) {
          bf16x4 pk;
          #pragma unroll
          for (int r = 0; r < 4; ++r) pk[r] = (bf16_t)acc[i][j][r];
          int m = m0 + wy * 64 + i * 16 + quad * 4;   // r=0 base; no 2048-cross
          int bq = m >> 11, pos = m & 2047;
          int d = j * 16 + l15;
          *(bf16x4*)(vT + (((size_t)(bq * 16 + head)) * 64 + d) * 2048 + pos) = pk;
        }
    }
  }
}

// ---------------------------------------------------------------------------
// Causal ReLU attention, R10: K staged (dbuf, swizzled global_load_lds),
// V fragments DIRECT from global vT (L2-resident via h-major grid) -> LDS
// 41KB -> 3 blocks/CU at (256,3). Sequential units (VGPR <= 3-waves/EU cap).
// Operand-swapped layouts (R8): S^T = K.Q^T (packed b64 Ss writes),
// O^T += V^T.S (packed b64 epilogue). Uniform 17 iterations per block.
// ---------------------------------------------------------------------------
__global__ __launch_bounds__(256, 3) void attn_kernel(
    const bf16_t* __restrict__ q, const bf16_t* __restrict__ k,
    const bf16_t* __restrict__ vT, bf16_t* __restrict__ out) {
  __shared__ __align__(16) bf16_t Ks[2][128 * 64];   // 2 x 16 KB (two 64-key halves)
  __shared__ __align__(16) bf16_t Ss[64 * 72];       // 9 KB, wave-private rows

  const int h = blockIdx.x, p = blockIdx.y, b = blockIdx.z;
  const int t = threadIdx.x;
  const int w = t >> 6, l = t & 63, l15 = l & 15, quad = l >> 4;
  const size_t bh = (size_t)(b * 16 + h);
  const int tB = 31 - p;

  const int r_l = l >> 3;            // row within 8-row chunk
  const int u_g = (l & 7) ^ r_l;     // swizzled source 8-elem unit
  const int rswz = l15 & 7;          // read-side swizzle key

  auto stage_k = [&](int buf, int half, int kt2) {
    #pragma unroll
    for (int c = 0; c < 2; ++c) {
      int idx = w * 2 + c;                    // 0..7
      int row = idx * 8 + r_l;                // 0..63
      async_copy16(&Ks[buf][half * 4096 + idx * 512],
                   k + (bh * 2048 + kt2 * 64 + row) * 64 + u_g * 8);
    }
  };
  auto stage_it = [&](int it, int buf) {
    if (it <= p) {
      stage_k(buf, 0, it);
    } else {
      int base = p + 1 + 2 * (it - p - 1);
      stage_k(buf, 0, base);
      int k2 = base + 1; if (k2 > 31) k2 = 31;  // clamp (compute skips > tB)
      stage_k(buf, 1, k2);
    }
  };

  // K fragments from staged LDS tile
  auto load_k = [&](const bf16_t* Kb, bf16x8 (&bk)[2][4]) {
    #pragma unroll
    for (int kk = 0; kk < 2; ++kk)
      #pragma unroll
      for (int tj = 0; tj < 4; ++tj)
        bk[kk][tj] = *(const bf16x8*)&Kb[(tj * 16 + l15) * 64 + (((kk * 4 + quad) ^ rswz) * 8)];
  };
  // V fragments direct from global vT (L2-resident)
  auto load_v = [&](int kt2, bf16x8 (&bv)[2][4]) {
    #pragma unroll
    for (int kk = 0; kk < 2; ++kk)
      #pragma unroll
      for (int tj = 0; tj < 4; ++tj)
        bv[kk][tj] = *(const bf16x8*)(vT + (bh * 64 + tj * 16 + l15) * 2048
                                         + kt2 * 64 + kk * 32 + quad * 8);
  };

  bf16x8 qa[2][2];   // B-operand fragments: lane l15 = query row, k = d
  {
    int rA = p * 64 + w * 16, rB = tB * 64 + w * 16;
    #pragma unroll
    for (int kk = 0; kk < 2; ++kk) {
      qa[0][kk] = *(const bf16x8*)(q + (bh * 2048 + rA + l15) * 64 + kk * 32 + quad * 8);
      qa[1][kk] = *(const bf16x8*)(q + (bh * 2048 + rB + l15) * 64 + kk * 32 + quad * 8);
    }
  }

  // acc[tj] = O^T block: lane col = i (l15), regs = d = tj*16 + quad*4 + r
  f32x4 acc0[4], acc1[4];
  #pragma unroll
  for (int tj = 0; tj < 4; ++tj) { acc0[tj] = (f32x4)0.0f; acc1[tj] = (f32x4)0.0f; }

  // one 64-key unit: S^T = K.Q^T, relu+mask (packed Ss write), O^T += V^T.S
  auto unit = [&](f32x4 (&accr)[4], bf16x8 (&qf)[2],
                  bf16x8 (&bk)[2][4], bf16x8 (&bv)[2][4], bool dg) {
    f32x4 sacc[4];  // sacc[tj]: lane col = i (l15), regs = j = tj*16+quad*4+r
    #pragma unroll
    for (int tj = 0; tj < 4; ++tj) sacc[tj] = (f32x4)0.0f;
    #pragma unroll
    for (int kk = 0; kk < 2; ++kk)
      #pragma unroll
      for (int tj = 0; tj < 4; ++tj)
        sacc[tj] = __builtin_amdgcn_mfma_f32_16x16x32_bf16(bk[kk][tj], qf[kk], sacc[tj], 0, 0, 0);
    #pragma unroll
    for (int tj = 0; tj < 4; ++tj) {
      bf16x4 pk;
      #pragma unroll
      for (int r = 0; r < 4; ++r) {
        float v = fmaxf(sacc[tj][r], 0.0f);
        if (dg && (tj * 16 + quad * 4 + r > w * 16 + l15)) v = 0.0f;
        pk[r] = (bf16_t)v;
      }
      *(bf16x4*)&Ss[(w * 16 + l15) * 72 + tj * 16 + quad * 4] = pk;
    }
    #pragma unroll
    for (int kk = 0; kk < 2; ++kk) {
      bf16x8 as_ = *(const bf16x8*)&Ss[(w * 16 + l15) * 72 + kk * 32 + quad * 8];
      #pragma unroll
      for (int tj = 0; tj < 4; ++tj)
        accr[tj] = __builtin_amdgcn_mfma_f32_16x16x32_bf16(bv[kk][tj], as_, accr[tj], 0, 0, 0);
    }
  };

  stage_it(0, 0);
  for (int it = 0; it < 17; ++it) {
    __syncthreads();  // drains this buffer's async loads; fences reuse
    if (it + 1 < 17) stage_it(it + 1, (it + 1) & 1);
    const int buf = it & 1;
    bf16x8 bk[2][4], bv[2][4];
    if (it <= p) {
      load_k(&Ks[buf][0], bk);
      load_v(it, bv);
      unit(acc0, qa[0], bk, bv, it == p);   // fragments shared by both units
      unit(acc1, qa[1], bk, bv, false);
    } else {
      int base = p + 1 + 2 * (it - p - 1);
      load_k(&Ks[buf][0], bk);
      load_v(base, bv);
      unit(acc1, qa[1], bk, bv, base == tB);
      if (base + 1 <= tB) {                 // sequential reuse: one set live
        load_k(&Ks[buf][4096], bk);
        load_v(base + 1, bv);
        unit(acc1, qa[1], bk, bv, base + 1 == tB);
      }
    }
  }

  // epilogue: O^T regs -> out[b][pos=i][h*64+d], 4 d-contiguous per store
  #pragma unroll
  for (int tj = 0; tj < 4; ++tj) {
    bf16x4 p0, p1;
    #pragma unroll
    for (int r = 0; r < 4; ++r) { p0[r] = (bf16_t)acc0[tj][r]; p1[r] = (bf16_t)acc1[tj][r]; }
    int posA = p * 64 + w * 16 + l15;
    int posB = tB * 64 + w * 16 + l15;
    int col = h * 64 + tj * 16 + quad * 4;
    *(bf16x4*)(out + ((size_t)b * 2048 + posA) * 1024 + col) = p0;
    *(bf16x4*)(out + ((size_t)b * 2048 + posB) * 1024 + col) = p1;
  }
}

// ---------------------------------------------------------------------------
// launch
// ---------------------------------------------------------------------------
extern "C" void kernel_launch(void* const* d_in, const int* in_sizes, int n_in,
                              void* d_out, int out_size, void* d_ws, size_t ws_size,
                              hipStream_t stream) {
  (void)in_sizes; (void)n_in; (void)out_size; (void)ws_size;
  const float* x     = (const float*)d_in[0];
  const float* ln1_g = (const float*)d_in[1];
  const float* ln1_b = (const float*)d_in[2];
  const float* w_qkv = (const float*)d_in[3];
  const float* w_out = (const float*)d_in[4];
  const float* ln2_g = (const float*)d_in[5];
  const float* ln2_b = (const float*)d_in[6];
  float* out = (float*)d_out;

  char* ws = (char*)d_ws;
  bf16_t* xn     = (bf16_t*)(ws + 0);          //  8,388,608  [4096,1024]
  bf16_t* wqkvT  = (bf16_t*)(ws + 8388608);    //  6,291,456  [3072,1024]
  bf16_t* woutT  = (bf16_t*)(ws + 14680064);   //  2,097,152  [1024,1024]
  bf16_t* qb     = (bf16_t*)(ws + 16777216);   //  8,388,608  [2,16,2048,64]
  bf16_t* kb     = (bf16_t*)(ws + 25165824);   //  8,388,608
  bf16_t* vTb    = (bf16_t*)(ws + 41943040);   //  8,388,608  [2,16,64,2048] (direct)
  bf16_t* ao     = (bf16_t*)(ws + 50331648);   //  8,388,608  [4096,1024]
  bf16_t* zb0    = (bf16_t*)(ws + 58720256);   //  8,388,608  [4096,1024] bf16 partial
  bf16_t* zb1    = (bf16_t*)(ws + 67108864);   //  8,388,608  bf16 partial

  prep_kernel<<<5120, 256, 0, stream>>>(x, ln1_g, ln1_b, xn, w_qkv, wqkvT, w_out, woutT);
  gemm128_kernel<1, 1><<<dim3(24, 32), 256, 0, stream>>>(xn, wqkvT, qb, kb, vTb);
  attn_kernel<<<dim3(16, 16, 2), 256, 0, stream>>>(qb, kb, vTb, ao);
  gemm128_kernel<0, 2><<<dim3(8, 32, 2), 256, 0, stream>>>(ao, woutT, zb0, zb1, nullptr);
  ln2_kernel<<<4096, 256, 0, stream>>>(zb0, zb1, ln2_g, ln2_b, out);
}

// Round 12
// 176.810 us; speedup vs baseline: 1.1858x; 1.1858x over previous
//
#include <hip/hip_runtime.h>
#include <cstdint>
#include <cstddef>

// ---------------------------------------------------------------------------
// ReLA block: y = LN2( (causal_relu( (LN1(x)Wq*s) (LN1(x)Wk)^T ) (LN1(x)Wv)) Wout )
// x: [2,2048,1024] fp32. HEADS=16, DIM_HEAD=64, DIM=1024. Output fp32.
// bf16 MFMA (16x16x32) everywhere, fp32 accumulate.
// R11 attention: uniform 33 single-unit iterations (A:0..p then B:0..31-p),
//   single-tile K+V dbuf staging -> LDS 41KB -> 3 blocks/CU at (256,3) with
//   only ONE fragment set live (no R6-style spill). V stays STAGED (R10's
//   direct-global V exposed ~250cyc VMEM latency per load in the MFMA
//   critical path -> 72µs). Direct-vT gemm epilogue (vtrans-free) retained.
// ---------------------------------------------------------------------------

typedef __bf16 bf16_t;
typedef __bf16 bf16x8 __attribute__((ext_vector_type(8)));
typedef __bf16 bf16x4 __attribute__((ext_vector_type(4)));
typedef float  f32x4  __attribute__((ext_vector_type(4)));

#define DEV_INLINE __device__ __forceinline__

// async global->LDS, 16B per lane. LDS dest is wave-uniform base + lane*16.
DEV_INLINE void async_copy16(void* lds, const void* g) {
  __builtin_amdgcn_global_load_lds(
      (__attribute__((address_space(1))) void*)(g),
      (__attribute__((address_space(3))) void*)(lds), 16, 0, 0);
}

// ---------------------------------------------------------------------------
// prep: fused LN1 (blocks 0..4095) + wtrans(w_qkv) (4096..4863) +
//       wtrans(w_out) (4864..5119)
// ---------------------------------------------------------------------------
__global__ __launch_bounds__(256) void prep_kernel(
    const float* __restrict__ x, const float* __restrict__ g1,
    const float* __restrict__ b1, bf16_t* __restrict__ xn,
    const float* __restrict__ w_qkv, bf16_t* __restrict__ wqkvT,
    const float* __restrict__ w_out, bf16_t* __restrict__ woutT) {
  const int bid = blockIdx.x;
  const int t = threadIdx.x;
  if (bid < 4096) {
    // ---- LN1 row ----
    const int w = t >> 6, l = t & 63;
    const float* xr = x + (size_t)bid * 1024;
    float4 v = *(const float4*)(xr + t * 4);
    float s  = v.x + v.y + v.z + v.w;
    float s2 = v.x * v.x + v.y * v.y + v.z * v.z + v.w * v.w;
    #pragma unroll
    for (int off = 32; off >= 1; off >>= 1) {
      s  += __shfl_down(s, off);
      s2 += __shfl_down(s2, off);
    }
    __shared__ float red[8];
    if (l == 0) { red[w] = s; red[4 + w] = s2; }
    __syncthreads();
    s  = red[0] + red[1] + red[2] + red[3];
    s2 = red[4] + red[5] + red[6] + red[7];
    float mu  = s * (1.0f / 1024.0f);
    float var = s2 * (1.0f / 1024.0f) - mu * mu;
    float rs  = rsqrtf(var + 1e-5f);
    float4 gv = *(const float4*)(g1 + t * 4);
    float4 bv = *(const float4*)(b1 + t * 4);
    bf16x4 o;
    o[0] = (bf16_t)((v.x - mu) * rs * gv.x + bv.x);
    o[1] = (bf16_t)((v.y - mu) * rs * gv.y + bv.y);
    o[2] = (bf16_t)((v.z - mu) * rs * gv.z + bv.z);
    o[3] = (bf16_t)((v.w - mu) * rs * gv.w + bv.w);
    *(bf16x4*)(xn + (size_t)bid * 1024 + t * 4) = o;
  } else {
    // ---- weight transpose+convert: 64x64 tile ----
    const float* wsrc; bf16_t* wdst; int N, tile;
    if (bid < 4864) { wsrc = w_qkv; wdst = wqkvT; N = 3072; tile = bid - 4096; }
    else            { wsrc = w_out; wdst = woutT; N = 1024; tile = bid - 4864; }
    const int ntiles = N >> 6;
    const int n0 = (tile % ntiles) * 64, k0 = (tile / ntiles) * 64;
    __shared__ __align__(16) float tl[64][68];
    #pragma unroll
    for (int c = 0; c < 4; ++c) {
      int idx = c * 256 + t;
      int r = idx >> 4, c4 = (idx & 15) * 4;
      *(float4*)&tl[r][c4] = *(const float4*)(wsrc + (size_t)(k0 + r) * N + n0 + c4);
    }
    __syncthreads();
    #pragma unroll
    for (int c = 0; c < 2; ++c) {
      int idx = c * 256 + t;
      int nl = idx >> 3, kc = (idx & 7) * 8;
      bf16x8 o;
      #pragma unroll
      for (int ii = 0; ii < 8; ++ii) o[ii] = (bf16_t)tl[kc + ii][nl];
      *(bf16x8*)(wdst + (size_t)(n0 + nl) * 1024 + k0 + kc) = o;
    }
  }
}

// ---------------------------------------------------------------------------
// LN2 (fused split-K add, bf16 partials): z = z0 + z1 -> layernorm -> fp32
// ---------------------------------------------------------------------------
__global__ __launch_bounds__(256) void ln2_kernel(
    const bf16_t* __restrict__ z0, const bf16_t* __restrict__ z1,
    const float* __restrict__ g, const float* __restrict__ bta,
    float* __restrict__ out) {
  const int row = blockIdx.x;
  const int t = threadIdx.x, w = t >> 6, l = t & 63;
  bf16x4 a0 = *(const bf16x4*)(z0 + (size_t)row * 1024 + t * 4);
  bf16x4 a1 = *(const bf16x4*)(z1 + (size_t)row * 1024 + t * 4);
  float4 v;
  v.x = (float)a0[0] + (float)a1[0];
  v.y = (float)a0[1] + (float)a1[1];
  v.z = (float)a0[2] + (float)a1[2];
  v.w = (float)a0[3] + (float)a1[3];
  float s  = v.x + v.y + v.z + v.w;
  float s2 = v.x * v.x + v.y * v.y + v.z * v.z + v.w * v.w;
  #pragma unroll
  for (int off = 32; off >= 1; off >>= 1) {
    s  += __shfl_down(s, off);
    s2 += __shfl_down(s2, off);
  }
  __shared__ float red[8];
  if (l == 0) { red[w] = s; red[4 + w] = s2; }
  __syncthreads();
  s  = red[0] + red[1] + red[2] + red[3];
  s2 = red[4] + red[5] + red[6] + red[7];
  float mu  = s * (1.0f / 1024.0f);
  float var = s2 * (1.0f / 1024.0f) - mu * mu;
  float rs  = rsqrtf(var + 1e-5f);
  float4 gv = *(const float4*)(g + t * 4);
  float4 bv = *(const float4*)(bta + t * 4);
  float4 o;
  o.x = (v.x - mu) * rs * gv.x + bv.x;
  o.y = (v.y - mu) * rs * gv.y + bv.y;
  o.z = (v.z - mu) * rs * gv.z + bv.z;
  o.w = (v.w - mu) * rs * gv.w + bv.w;
  *(float4*)(out + (size_t)row * 1024 + t * 4) = o;
}

// ---------------------------------------------------------------------------
// GEMM: C[M,N] = A[M,1024] @ Bt[N,1024]^T, bf16 in, fp32 acc.
// BK=64, XOR-swizzled staging. KSPLIT=2: kz=0 -> C0, kz=1 -> C1 (bf16
// partials). EPI=1: qkv epilogue -> q(*0.125)/k as [b,h,2048,64] bf16,
// v directly TRANSPOSED as vT [b,h,64,2048] (packed bf16x4, r = pos).
// ---------------------------------------------------------------------------
template <int EPI, int KSPLIT>
__global__ __launch_bounds__(256, 3) void gemm128_kernel(
    const bf16_t* __restrict__ A, const bf16_t* __restrict__ Bt,
    void* __restrict__ C0, void* __restrict__ C1, void* __restrict__ C2) {
  __shared__ __align__(16) bf16_t As[128 * 64];  // 16 KB
  __shared__ __align__(16) bf16_t Bs[128 * 64];  // 16 KB
  const int t = threadIdx.x;
  const int w = t >> 6, l = t & 63, l15 = l & 15, quad = l >> 4;
  const int wy = w >> 1, wx = w & 1;
  const int m0 = blockIdx.y * 128, n0 = blockIdx.x * 128;
  const int kz = (KSPLIT > 1) ? blockIdx.z : 0;
  const int kt0 = kz * (16 / KSPLIT), kt1 = kt0 + (16 / KSPLIT);

  const int r_l = l >> 3;              // row within 8-row chunk
  const int u_src = (l & 7) ^ r_l;     // swizzled source 8-elem unit
  const int rswz = l15 & 7;            // read-side swizzle key

  f32x4 acc[4][4];
  #pragma unroll
  for (int i = 0; i < 4; ++i)
    #pragma unroll
    for (int j = 0; j < 4; ++j) acc[i][j] = (f32x4)0.0f;

  for (int kt = kt0; kt < kt1; ++kt) {
    __syncthreads();
    #pragma unroll
    for (int c = 0; c < 4; ++c) {
      int idx = w * 4 + c;             // 16 chunks of 512 elems
      int row = idx * 8 + r_l;         // 0..127
      async_copy16(&As[idx * 512], A + (size_t)(m0 + row) * 1024 + kt * 64 + u_src * 8);
      async_copy16(&Bs[idx * 512], Bt + (size_t)(n0 + row) * 1024 + kt * 64 + u_src * 8);
    }
    __syncthreads();
    #pragma unroll
    for (int kk = 0; kk < 2; ++kk) {
      bf16x8 af[4], bfr[4];
      #pragma unroll
      for (int i = 0; i < 4; ++i)
        af[i] = *(const bf16x8*)&As[(wy * 64 + i * 16 + l15) * 64 + (((kk * 4 + quad) ^ rswz) * 8)];
      #pragma unroll
      for (int j = 0; j < 4; ++j)
        bfr[j] = *(const bf16x8*)&Bs[(wx * 64 + j * 16 + l15) * 64 + (((kk * 4 + quad) ^ rswz) * 8)];
      #pragma unroll
      for (int i = 0; i < 4; ++i)
        #pragma unroll
        for (int j = 0; j < 4; ++j)
          acc[i][j] = __builtin_amdgcn_mfma_f32_16x16x32_bf16(af[i], bfr[j], acc[i][j], 0, 0, 0);
    }
  }

  if (EPI == 0) {
    bf16_t* C = (bf16_t*)(kz == 0 ? C0 : C1);   // bf16 partial destinations
    #pragma unroll
    for (int i = 0; i < 4; ++i)
      #pragma unroll
      for (int j = 0; j < 4; ++j)
        #pragma unroll
        for (int r = 0; r < 4; ++r) {
          int m = m0 + wy * 64 + i * 16 + quad * 4 + r;
          int n = n0 + wx * 64 + j * 16 + l15;
          C[(size_t)m * 1024 + n] = (bf16_t)acc[i][j][r];
        }
  } else {
    int nb = n0 + wx * 64;
    int which = nb >> 10;                 // 0=q, 1=k, 2=v
    int head = (nb & 1023) >> 6;
    if (which < 2) {
      bf16_t* dst = which == 0 ? (bf16_t*)C0 : (bf16_t*)C1;
      float sc = which == 0 ? 0.125f : 1.0f;
      #pragma unroll
      for (int i = 0; i < 4; ++i)
        #pragma unroll
        for (int j = 0; j < 4; ++j)
          #pragma unroll
          for (int r = 0; r < 4; ++r) {
            int m = m0 + wy * 64 + i * 16 + quad * 4 + r;
            int bq = m >> 11, pos = m & 2047;
            int d = j * 16 + l15;
            dst[(((size_t)(bq * 16 + head)) * 2048 + pos) * 64 + d] =
                (bf16_t)(acc[i][j][r] * sc);
          }
    } else {
      // v written directly transposed: vT[b,h,64,2048]; reg r = pos-contig
      bf16_t* vT = (bf16_t*)C2;
      #pragma unroll
      for (int i = 0; i < 4; ++i)
        #pragma unroll
        for (int j = 0; j < 4; ++j) {
          bf16x4 pk;
          #pragma unroll
          for (int r = 0; r < 4; ++r) pk[r] = (bf16_t)acc[i][j][r];
          int m = m0 + wy * 64 + i * 16 + quad * 4;   // r=0 base; no 2048-cross
          int bq = m >> 11, pos = m & 2047;
          int d = j * 16 + l15;
          *(bf16x4*)(vT + (((size_t)(bq * 16 + head)) * 64 + d) * 2048 + pos) = pk;
        }
    }
  }
}

// ---------------------------------------------------------------------------
// Causal ReLU attention, R11: uniform 33 single-unit iterations.
// Block (h=bx, p=by, b=bz): units = (A=p, kt=0..p) then (B=31-p, kt=0..tB),
// exactly 33 per block. Single 64-key tile staged per iteration (K+V, dbuf)
// via swizzled global_load_lds -> LDS 41KB -> 3 blocks/CU at (256,3); one
// fragment set live (~150 VGPR, no spill). Operand-swapped layouts (R8):
// S^T = K.Q^T (packed b64 Ss writes), O^T += V^T.S (packed b64 epilogue).
// ---------------------------------------------------------------------------
__global__ __launch_bounds__(256, 3) void attn_kernel(
    const bf16_t* __restrict__ q, const bf16_t* __restrict__ k,
    const bf16_t* __restrict__ vT, bf16_t* __restrict__ out) {
  __shared__ __align__(16) bf16_t Ks[2][64 * 64];   // 2 x 8 KB
  __shared__ __align__(16) bf16_t Vts[2][64 * 64];  // 2 x 8 KB
  __shared__ __align__(16) bf16_t Ss[64 * 72];      // 9 KB, wave-private rows

  const int h = blockIdx.x, p = blockIdx.y, b = blockIdx.z;
  const int t = threadIdx.x;
  const int w = t >> 6, l = t & 63, l15 = l & 15, quad = l >> 4;
  const size_t bh = (size_t)(b * 16 + h);
  const int tB = 31 - p;
  const int nit = 33;

  const int r_l = l >> 3;            // row within 8-row chunk
  const int u_g = (l & 7) ^ r_l;     // swizzled source 8-elem unit
  const int rswz = l15 & 7;          // read-side swizzle key

  // stage the K+V tile for iteration `it` into buffer `buf`
  auto stage_it = [&](int it, int buf) {
    int kt2 = (it <= p) ? it : (it - p - 1);
    #pragma unroll
    for (int c = 0; c < 2; ++c) {
      int idx = w * 2 + c;                    // 0..7
      int row = idx * 8 + r_l;                // 0..63
      async_copy16(&Ks[buf][idx * 512],
                   k + (bh * 2048 + kt2 * 64 + row) * 64 + u_g * 8);
      async_copy16(&Vts[buf][idx * 512],
                   vT + (bh * 64 + row) * 2048 + kt2 * 64 + u_g * 8);
    }
  };

  // K/V fragments from the staged tile (one set live)
  auto load_lds = [&](int buf, bf16x8 (&bk)[2][4], bf16x8 (&bv)[2][4]) {
    #pragma unroll
    for (int kk = 0; kk < 2; ++kk)
      #pragma unroll
      for (int tj = 0; tj < 4; ++tj) {
        int u = ((kk * 4 + quad) ^ rswz) * 8;
        bk[kk][tj] = *(const bf16x8*)&Ks[buf][(tj * 16 + l15) * 64 + u];
        bv[kk][tj] = *(const bf16x8*)&Vts[buf][(tj * 16 + l15) * 64 + u];
      }
  };

  bf16x8 qa[2][2];   // B-operand fragments: lane l15 = query row, k = d
  {
    int rA = p * 64 + w * 16, rB = tB * 64 + w * 16;
    #pragma unroll
    for (int kk = 0; kk < 2; ++kk) {
      qa[0][kk] = *(const bf16x8*)(q + (bh * 2048 + rA + l15) * 64 + kk * 32 + quad * 8);
      qa[1][kk] = *(const bf16x8*)(q + (bh * 2048 + rB + l15) * 64 + kk * 32 + quad * 8);
    }
  }

  // acc[tj] = O^T block: lane col = i (l15), regs = d = tj*16 + quad*4 + r
  f32x4 acc0[4], acc1[4];
  #pragma unroll
  for (int tj = 0; tj < 4; ++tj) { acc0[tj] = (f32x4)0.0f; acc1[tj] = (f32x4)0.0f; }

  // one 64-key unit: S^T = K.Q^T, relu+mask (packed Ss write), O^T += V^T.S
  auto unit = [&](f32x4 (&accr)[4], bf16x8 (&qf)[2],
                  bf16x8 (&bk)[2][4], bf16x8 (&bv)[2][4], bool dg) {
    f32x4 sacc[4];  // sacc[tj]: lane col = i (l15), regs = j = tj*16+quad*4+r
    #pragma unroll
    for (int tj = 0; tj < 4; ++tj) sacc[tj] = (f32x4)0.0f;
    #pragma unroll
    for (int kk = 0; kk < 2; ++kk)
      #pragma unroll
      for (int tj = 0; tj < 4; ++tj)
        sacc[tj] = __builtin_amdgcn_mfma_f32_16x16x32_bf16(bk[kk][tj], qf[kk], sacc[tj], 0, 0, 0);
    #pragma unroll
    for (int tj = 0; tj < 4; ++tj) {
      bf16x4 pk;
      #pragma unroll
      for (int r = 0; r < 4; ++r) {
        float v = fmaxf(sacc[tj][r], 0.0f);
        if (dg && (tj * 16 + quad * 4 + r > w * 16 + l15)) v = 0.0f;
        pk[r] = (bf16_t)v;
      }
      *(bf16x4*)&Ss[(w * 16 + l15) * 72 + tj * 16 + quad * 4] = pk;
    }
    #pragma unroll
    for (int kk = 0; kk < 2; ++kk) {
      bf16x8 as_ = *(const bf16x8*)&Ss[(w * 16 + l15) * 72 + kk * 32 + quad * 8];
      #pragma unroll
      for (int tj = 0; tj < 4; ++tj)
        accr[tj] = __builtin_amdgcn_mfma_f32_16x16x32_bf16(bv[kk][tj], as_, accr[tj], 0, 0, 0);
    }
  };

  stage_it(0, 0);
  for (int it = 0; it < nit; ++it) {
    __syncthreads();  // drains this buffer's async loads; fences reuse
    if (it + 1 < nit) stage_it(it + 1, (it + 1) & 1);
    const int buf = it & 1;
    bf16x8 bk[2][4], bv[2][4];
    load_lds(buf, bk, bv);
    if (it <= p) {          // block-uniform branch; static acc/qa indexing
      unit(acc0, qa[0], bk, bv, it == p);
    } else {
      unit(acc1, qa[1], bk, bv, it - p - 1 == tB);
    }
  }

  // epilogue: O^T regs -> out[b][pos=i][h*64+d], 4 d-contiguous per store
  #pragma unroll
  for (int tj = 0; tj < 4; ++tj) {
    bf16x4 p0, p1;
    #pragma unroll
    for (int r = 0; r < 4; ++r) { p0[r] = (bf16_t)acc0[tj][r]; p1[r] = (bf16_t)acc1[tj][r]; }
    int posA = p * 64 + w * 16 + l15;
    int posB = tB * 64 + w * 16 + l15;
    int col = h * 64 + tj * 16 + quad * 4;
    *(bf16x4*)(out + ((size_t)b * 2048 + posA) * 1024 + col) = p0;
    *(bf16x4*)(out + ((size_t)b * 2048 + posB) * 1024 + col) = p1;
  }
}

// ---------------------------------------------------------------------------
// launch
// ---------------------------------------------------------------------------
extern "C" void kernel_launch(void* const* d_in, const int* in_sizes, int n_in,
                              void* d_out, int out_size, void* d_ws, size_t ws_size,
                              hipStream_t stream) {
  (void)in_sizes; (void)n_in; (void)out_size; (void)ws_size;
  const float* x     = (const float*)d_in[0];
  const float* ln1_g = (const float*)d_in[1];
  const float* ln1_b = (const float*)d_in[2];
  const float* w_qkv = (const float*)d_in[3];
  const float* w_out = (const float*)d_in[4];
  const float* ln2_g = (const float*)d_in[5];
  const float* ln2_b = (const float*)d_in[6];
  float* out = (float*)d_out;

  char* ws = (char*)d_ws;
  bf16_t* xn     = (bf16_t*)(ws + 0);          //  8,388,608  [4096,1024]
  bf16_t* wqkvT  = (bf16_t*)(ws + 8388608);    //  6,291,456  [3072,1024]
  bf16_t* woutT  = (bf16_t*)(ws + 14680064);   //  2,097,152  [1024,1024]
  bf16_t* qb     = (bf16_t*)(ws + 16777216);   //  8,388,608  [2,16,2048,64]
  bf16_t* kb     = (bf16_t*)(ws + 25165824);   //  8,388,608
  bf16_t* vTb    = (bf16_t*)(ws + 41943040);   //  8,388,608  [2,16,64,2048] (direct)
  bf16_t* ao     = (bf16_t*)(ws + 50331648);   //  8,388,608  [4096,1024]
  bf16_t* zb0    = (bf16_t*)(ws + 58720256);   //  8,388,608  [4096,1024] bf16 partial
  bf16_t* zb1    = (bf16_t*)(ws + 67108864);   //  8,388,608  bf16 partial

  prep_kernel<<<5120, 256, 0, stream>>>(x, ln1_g, ln1_b, xn, w_qkv, wqkvT, w_out, woutT);
  gemm128_kernel<1, 1><<<dim3(24, 32), 256, 0, stream>>>(xn, wqkvT, qb, kb, vTb);
  attn_kernel<<<dim3(16, 16, 2), 256, 0, stream>>>(qb, kb, vTb, ao);
  gemm128_kernel<0, 2><<<dim3(8, 32, 2), 256, 0, stream>>>(ao, woutT, zb0, zb1, nullptr);
  ln2_kernel<<<4096, 256, 0, stream>>>(zb0, zb1, ln2_g, ln2_b, out);
}